// Round 1
// baseline (439.344 us; speedup 1.0000x reference)
//
#include <hip/hip_runtime.h>
#include <math.h>

#define NN 128
#define HH 512
#define MM 2048
#define DD 128
#define EPSF 1e-8f

// ---------------- workspace layout (floats) ----------------
// k   : [NN*DD]        off 0
// kn  : [NN]           off 16384
// beta: [NN]           off 16512
// sx  : [NN*MM]        off 16640     (scores -> softmax weights in place)
// sc  : [NN*MM]        off 278784
// rp  : [8*NN*DD]      off 540928    (partial r sums, 8 m-chunks)
// e   : [NN*DD]        off 672000
// v   : [NN*DD]        off 688384
// total 704768 floats = 2.82 MB

// ---------- k1: k = h @ Wk^T + bk ; kn = max(||k||, eps) ; beta ----------
__global__ void k1_kbeta(const float* __restrict__ h, const float* __restrict__ Wk,
                         const float* __restrict__ bk, const float* __restrict__ Wb,
                         const float* __restrict__ bb, float* __restrict__ k,
                         float* __restrict__ kn, float* __restrict__ beta) {
    int n = blockIdx.x;
    int t = threadIdx.x;            // 128 threads
    __shared__ float hs[HH];
    __shared__ float red[128];
    for (int i = t; i < HH; i += 128) hs[i] = h[n * HH + i];
    __syncthreads();
    // k[n, t]
    float acc = bk[t];
    const float* wr = Wk + t * HH;
    for (int hh = 0; hh < HH; hh += 4) {
        float4 w4 = *(const float4*)(wr + hh);
        acc += w4.x * hs[hh] + w4.y * hs[hh + 1] + w4.z * hs[hh + 2] + w4.w * hs[hh + 3];
    }
    k[n * DD + t] = acc;
    red[t] = acc * acc;
    __syncthreads();
    for (int s = 64; s > 0; s >>= 1) { if (t < s) red[t] += red[t + s]; __syncthreads(); }
    if (t == 0) kn[n] = fmaxf(sqrtf(red[0]), EPSF);
    __syncthreads();
    // beta
    float b = 0.f;
    for (int i = t; i < HH; i += 128) b += hs[i] * Wb[i];
    red[t] = b;
    __syncthreads();
    for (int s = 64; s > 0; s >>= 1) { if (t < s) red[t] += red[t + s]; __syncthreads(); }
    if (t == 0) {
        float bp   = red[0] + bb[0];
        float bpos = fmaxf(bp, 0.f);
        float bneg = fminf(bp, 0.f);
        // log1p(exp(bneg)) + bpos + log1p(exp(-bpos)) + (1 - ln2)
        beta[n] = log1pf(expf(bneg)) + bpos + log1pf(expf(-bpos))
                + (1.f - 0.69314718055994530942f);
    }
}

// ---------- k2: cosine scores * beta for c_xf and c_prev (one pass) ----------
__global__ void k2_scores(const float* __restrict__ c_prev, const float* __restrict__ c_xf,
                          const float* __restrict__ k, const float* __restrict__ kn,
                          const float* __restrict__ beta, float* __restrict__ sx,
                          float* __restrict__ sc) {
    int gid  = blockIdx.x;          // NN*MM/8 blocks, 8 m per block
    int n    = gid >> 8;            // 256 blocks per n
    int mb   = (gid & 255) << 3;
    int t    = threadIdx.x;         // 256
    int sub  = t >> 5;              // 0..7 -> which m
    int lane = t & 31;
    int m    = mb + sub;
    int nm   = n * MM + m;
    int base = (nm << 7) + lane * 4;   // *DD
    float4 k4 = *(const float4*)(k + n * DD + lane * 4);
    float4 a  = *(const float4*)(c_xf + base);
    float4 b  = *(const float4*)(c_prev + base);
    float dx = a.x * k4.x + a.y * k4.y + a.z * k4.z + a.w * k4.w;
    float nx = a.x * a.x + a.y * a.y + a.z * a.z + a.w * a.w;
    float dc = b.x * k4.x + b.y * k4.y + b.z * k4.z + b.w * k4.w;
    float nc = b.x * b.x + b.y * b.y + b.z * b.z + b.w * b.w;
    for (int off = 16; off > 0; off >>= 1) {
        dx += __shfl_xor(dx, off, 32);
        nx += __shfl_xor(nx, off, 32);
        dc += __shfl_xor(dc, off, 32);
        nc += __shfl_xor(nc, off, 32);
    }
    if (lane == 0) {
        float s = beta[n] / kn[n];
        sx[nm] = dx / fmaxf(sqrtf(nx), EPSF) * s;
        sc[nm] = dc / fmaxf(sqrtf(nc), EPSF) * s;
    }
}

// ---------- k3: row softmax over M, in place (blockIdx: 2*NN) ----------
__global__ void k3_softmax(float* __restrict__ sx, float* __restrict__ sc) {
    int bx = blockIdx.x;
    float* s = ((bx & 1) ? sc : sx) + (bx >> 1) * MM;
    int t = threadIdx.x;            // 256, 8 elems each
    float vals[8];
    float mx = -1e30f;
    for (int i = 0; i < 8; i++) { vals[i] = s[t + i * 256]; mx = fmaxf(mx, vals[i]); }
    __shared__ float red[256];
    red[t] = mx;
    __syncthreads();
    for (int st = 128; st > 0; st >>= 1) { if (t < st) red[t] = fmaxf(red[t], red[t + st]); __syncthreads(); }
    mx = red[0];
    __syncthreads();
    float sum = 0.f;
    for (int i = 0; i < 8; i++) { vals[i] = expf(vals[i] - mx); sum += vals[i]; }
    red[t] = sum;
    __syncthreads();
    for (int st = 128; st > 0; st >>= 1) { if (t < st) red[t] += red[t + st]; __syncthreads(); }
    float inv = 1.f / red[0];
    for (int i = 0; i < 8; i++) s[t + i * 256] = vals[i] * inv;
}

// ---------- k4: partial r = sum_m w_kx * c_xf (8 chunks per n) ----------
__global__ void k4_r(const float* __restrict__ c_xf, const float* __restrict__ wx,
                     float* __restrict__ rp) {
    int b = blockIdx.x;             // NN*8
    int n = b >> 3;
    int c = b & 7;
    int t = threadIdx.x;            // 256
    int d = t & 127, half = t >> 7;
    float acc = 0.f;
    int mbase = c * 256;
    for (int mm = half; mm < 256; mm += 2) {
        int nm = n * MM + mbase + mm;
        acc += wx[nm] * c_xf[(nm << 7) + d];
    }
    __shared__ float red[256];
    red[t] = acc;
    __syncthreads();
    if (t < 128) rp[(c * NN + n) * DD + t] = red[t] + red[t + 128];
}

// ---------- k5: GRU cell + e, v ----------
__global__ void k5_gru(const float* __restrict__ hprev, const float* __restrict__ rp,
                       const float* __restrict__ Wih, const float* __restrict__ Whh,
                       const float* __restrict__ bih, const float* __restrict__ bhh,
                       const float* __restrict__ We, const float* __restrict__ be,
                       const float* __restrict__ Wv, const float* __restrict__ bv,
                       float* __restrict__ ho_out, float* __restrict__ e,
                       float* __restrict__ v) {
    int n = blockIdx.x;
    int t = threadIdx.x;            // 256
    __shared__ float hs[HH];
    __shared__ float rs[DD];
    __shared__ float hos[HH];
    for (int i = t; i < HH; i += 256) hs[i] = hprev[n * HH + i];
    if (t < DD) {
        float a = 0.f;
        for (int c = 0; c < 8; c++) a += rp[(c * NN + n) * DD + t];
        rs[t] = a;
    }
    __syncthreads();
    for (int j = t; j < HH; j += 256) {
        float ir = bih[j], iz = bih[j + HH], inn = bih[j + 2 * HH];
        const float* wr = Wih + j * DD;
        const float* wz = Wih + (j + HH) * DD;
        const float* wn = Wih + (j + 2 * HH) * DD;
        for (int dd = 0; dd < DD; dd += 4) {
            float4 r4 = *(const float4*)(rs + dd);
            float4 a4 = *(const float4*)(wr + dd);
            float4 b4 = *(const float4*)(wz + dd);
            float4 c4 = *(const float4*)(wn + dd);
            ir  += a4.x * r4.x + a4.y * r4.y + a4.z * r4.z + a4.w * r4.w;
            iz  += b4.x * r4.x + b4.y * r4.y + b4.z * r4.z + b4.w * r4.w;
            inn += c4.x * r4.x + c4.y * r4.y + c4.z * r4.z + c4.w * r4.w;
        }
        float hr = bhh[j], hz = bhh[j + HH], hn = bhh[j + 2 * HH];
        const float* ur = Whh + j * HH;
        const float* uz = Whh + (j + HH) * HH;
        const float* un = Whh + (j + 2 * HH) * HH;
        for (int hh = 0; hh < HH; hh += 4) {
            float4 h4 = *(const float4*)(hs + hh);
            float4 a4 = *(const float4*)(ur + hh);
            float4 b4 = *(const float4*)(uz + hh);
            float4 c4 = *(const float4*)(un + hh);
            hr += a4.x * h4.x + a4.y * h4.y + a4.z * h4.z + a4.w * h4.w;
            hz += b4.x * h4.x + b4.y * h4.y + b4.z * h4.z + b4.w * h4.w;
            hn += c4.x * h4.x + c4.y * h4.y + c4.z * h4.z + c4.w * h4.w;
        }
        float rg = 1.f / (1.f + expf(-(ir + hr)));
        float zg = 1.f / (1.f + expf(-(iz + hz)));
        float ng = tanhf(inn + rg * hn);
        float ho = (1.f - zg) * ng + zg * hs[j];
        hos[j] = ho;
        ho_out[n * HH + j] = ho;
    }
    __syncthreads();
    if (t < DD) {
        float ea = be[t], va = bv[t];
        const float* we = We + t * HH;
        const float* wv = Wv + t * HH;
        for (int hh = 0; hh < HH; hh += 4) {
            float4 h4 = *(const float4*)(hos + hh);
            float4 e4 = *(const float4*)(we + hh);
            float4 v4 = *(const float4*)(wv + hh);
            ea += e4.x * h4.x + e4.y * h4.y + e4.z * h4.z + e4.w * h4.w;
            va += v4.x * h4.x + v4.y * h4.y + v4.z * h4.z + v4.w * h4.w;
        }
        e[n * DD + t] = 1.f / (1.f + expf(-ea));
        v[n * DD + t] = va;
    }
}

// ---------- k6: c_new = c_prev*(1 - w*e) + w*v ----------
__global__ void k6_cnew(const float* __restrict__ c_prev, const float* __restrict__ wc,
                        const float* __restrict__ e, const float* __restrict__ v,
                        float* __restrict__ out) {
    int i  = blockIdx.x * 256 + threadIdx.x;   // float4 index, NN*MM*DD/4 total
    int nm = i >> 5;                            // DD/4 = 32
    int d4 = i & 31;
    int n  = nm >> 11;                          // MM = 2048
    float w = wc[nm];
    float4 c4 = ((const float4*)c_prev)[i];
    float4 e4 = ((const float4*)e)[n * 32 + d4];
    float4 v4 = ((const float4*)v)[n * 32 + d4];
    float4 o;
    o.x = c4.x * (1.f - w * e4.x) + w * v4.x;
    o.y = c4.y * (1.f - w * e4.y) + w * v4.y;
    o.z = c4.z * (1.f - w * e4.z) + w * v4.z;
    o.w = c4.w * (1.f - w * e4.w) + w * v4.w;
    ((float4*)out)[i] = o;
}

extern "C" void kernel_launch(void* const* d_in, const int* in_sizes, int n_in,
                              void* d_out, int out_size, void* d_ws, size_t ws_size,
                              hipStream_t stream) {
    const float* h_o_prev = (const float*)d_in[0];
    const float* c_prev   = (const float*)d_in[1];
    const float* c_xf     = (const float*)d_in[2];
    const float* Wk       = (const float*)d_in[3];
    const float* bk       = (const float*)d_in[4];
    const float* Wb       = (const float*)d_in[5];
    const float* bb       = (const float*)d_in[6];
    const float* We       = (const float*)d_in[7];
    const float* be       = (const float*)d_in[8];
    const float* Wv       = (const float*)d_in[9];
    const float* bv       = (const float*)d_in[10];
    const float* Wih      = (const float*)d_in[11];
    const float* Whh      = (const float*)d_in[12];
    const float* bih      = (const float*)d_in[13];
    const float* bhh      = (const float*)d_in[14];

    float* ws   = (float*)d_ws;
    float* k    = ws;
    float* kn   = ws + 16384;
    float* beta = ws + 16512;
    float* sx   = ws + 16640;
    float* sc   = ws + 278784;
    float* rp   = ws + 540928;
    float* e    = ws + 672000;
    float* v    = ws + 688384;

    float* ho_out = (float*)d_out;              // [NN*HH]
    float* c_out  = (float*)d_out + NN * HH;    // [NN*MM*DD]

    k1_kbeta<<<NN, 128, 0, stream>>>(h_o_prev, Wk, bk, Wb, bb, k, kn, beta);
    k2_scores<<<NN * MM / 8, 256, 0, stream>>>(c_prev, c_xf, k, kn, beta, sx, sc);
    k3_softmax<<<2 * NN, 256, 0, stream>>>(sx, sc);
    k4_r<<<NN * 8, 256, 0, stream>>>(c_xf, sx, rp);
    k5_gru<<<NN, 256, 0, stream>>>(h_o_prev, rp, Wih, Whh, bih, bhh, We, be, Wv, bv,
                                   ho_out, e, v);
    k6_cnew<<<NN * MM * DD / 4 / 256, 256, 0, stream>>>(c_prev, sc, e, v, c_out);
}

// Round 2
// 194.989 us; speedup vs baseline: 2.2532x; 2.2532x over previous
//
#include <hip/hip_runtime.h>
#include <math.h>

#define NN 128
#define HH 512
#define MM 2048
#define DD 128
#define EPSF 1e-8f

// ---------------- workspace layout (floats) ----------------
// k   : [NN*DD]        off 0
// kn  : [NN]           off 16384
// beta: [NN]           off 16512
// sx  : [NN*MM]        off 16640   (scores -> softmax wx; later reused as A)
// sc  : [NN*MM]        off 278784
// rp  : [8*NN*DD]      off 540928
// B   : [NN*1536]      off 672000  (gh pre-gates)
// e   : [NN*DD]        off 868608
// v   : [NN*DD]        off 884992
// total 901376 floats = 3.6 MB
// A (gi pre-gates, NN*1536=196608) aliases sx (262144): sx is dead after k4.

__global__ void k1_kbeta(const float* __restrict__ h, const float* __restrict__ Wk,
                         const float* __restrict__ bk, const float* __restrict__ Wb,
                         const float* __restrict__ bb, float* __restrict__ k,
                         float* __restrict__ kn, float* __restrict__ beta) {
    int n = blockIdx.x;
    int t = threadIdx.x;            // 128 threads
    __shared__ float hs[HH];
    __shared__ float red[128];
    for (int i = t; i < HH; i += 128) hs[i] = h[n * HH + i];
    __syncthreads();
    float acc = bk[t];
    const float* wr = Wk + t * HH;
    for (int hh = 0; hh < HH; hh += 4) {
        float4 w4 = *(const float4*)(wr + hh);
        acc += w4.x * hs[hh] + w4.y * hs[hh + 1] + w4.z * hs[hh + 2] + w4.w * hs[hh + 3];
    }
    k[n * DD + t] = acc;
    red[t] = acc * acc;
    __syncthreads();
    for (int s = 64; s > 0; s >>= 1) { if (t < s) red[t] += red[t + s]; __syncthreads(); }
    if (t == 0) kn[n] = fmaxf(sqrtf(red[0]), EPSF);
    __syncthreads();
    float b = 0.f;
    for (int i = t; i < HH; i += 128) b += hs[i] * Wb[i];
    red[t] = b;
    __syncthreads();
    for (int s = 64; s > 0; s >>= 1) { if (t < s) red[t] += red[t + s]; __syncthreads(); }
    if (t == 0) {
        float bp   = red[0] + bb[0];
        float bpos = fmaxf(bp, 0.f);
        float bneg = fminf(bp, 0.f);
        beta[n] = log1pf(expf(bneg)) + bpos + log1pf(expf(-bpos))
                + (1.f - 0.69314718055994530942f);
    }
}

__global__ void k2_scores(const float* __restrict__ c_prev, const float* __restrict__ c_xf,
                          const float* __restrict__ k, const float* __restrict__ kn,
                          const float* __restrict__ beta, float* __restrict__ sx,
                          float* __restrict__ sc) {
    int gid  = blockIdx.x;          // NN*MM/8 blocks, 8 m per block
    int n    = gid >> 8;
    int mb   = (gid & 255) << 3;
    int t    = threadIdx.x;         // 256
    int sub  = t >> 5;
    int lane = t & 31;
    int m    = mb + sub;
    int nm   = n * MM + m;
    int base = (nm << 7) + lane * 4;
    float4 k4 = *(const float4*)(k + n * DD + lane * 4);
    float4 a  = *(const float4*)(c_xf + base);
    float4 b  = *(const float4*)(c_prev + base);
    float dx = a.x * k4.x + a.y * k4.y + a.z * k4.z + a.w * k4.w;
    float nx = a.x * a.x + a.y * a.y + a.z * a.z + a.w * a.w;
    float dc = b.x * k4.x + b.y * k4.y + b.z * k4.z + b.w * k4.w;
    float nc = b.x * b.x + b.y * b.y + b.z * b.z + b.w * b.w;
    for (int off = 16; off > 0; off >>= 1) {
        dx += __shfl_xor(dx, off, 32);
        nx += __shfl_xor(nx, off, 32);
        dc += __shfl_xor(dc, off, 32);
        nc += __shfl_xor(nc, off, 32);
    }
    if (lane == 0) {
        float s = beta[n] / kn[n];
        sx[nm] = dx / fmaxf(sqrtf(nx), EPSF) * s;
        sc[nm] = dc / fmaxf(sqrtf(nc), EPSF) * s;
    }
}

__global__ void k3_softmax(float* __restrict__ sx, float* __restrict__ sc) {
    int bx = blockIdx.x;
    float* s = ((bx & 1) ? sc : sx) + (bx >> 1) * MM;
    int t = threadIdx.x;            // 256
    float vals[8];
    float mx = -1e30f;
    for (int i = 0; i < 8; i++) { vals[i] = s[t + i * 256]; mx = fmaxf(mx, vals[i]); }
    __shared__ float red[256];
    red[t] = mx;
    __syncthreads();
    for (int st = 128; st > 0; st >>= 1) { if (t < st) red[t] = fmaxf(red[t], red[t + st]); __syncthreads(); }
    mx = red[0];
    __syncthreads();
    float sum = 0.f;
    for (int i = 0; i < 8; i++) { vals[i] = expf(vals[i] - mx); sum += vals[i]; }
    red[t] = sum;
    __syncthreads();
    for (int st = 128; st > 0; st >>= 1) { if (t < st) red[t] += red[t + st]; __syncthreads(); }
    float inv = 1.f / red[0];
    for (int i = 0; i < 8; i++) s[t + i * 256] = vals[i] * inv;
}

__global__ void k4_r(const float* __restrict__ c_xf, const float* __restrict__ wx,
                     float* __restrict__ rp) {
    int b = blockIdx.x;             // NN*8
    int n = b >> 3;
    int c = b & 7;
    int t = threadIdx.x;            // 256
    int d = t & 127, half = t >> 7;
    float acc = 0.f;
    int mbase = c * 256;
    for (int mm = half; mm < 256; mm += 2) {
        int nm = n * MM + mbase + mm;
        acc += wx[nm] * c_xf[(nm << 7) + d];
    }
    __shared__ float red[256];
    red[t] = acc;
    __syncthreads();
    if (t < 128) rp[(c * NN + n) * DD + t] = red[t] + red[t + 128];
}

// ---------- g1: A = r@Wih^T + bih, B = h@Whh^T + bhh  ([NN,1536] each) ----------
// grid 768 = 96 j-tiles x 8 n-tiles; block 256 = 16j x 16n; K chunks: 1x128(r/Wih) + 4x128(h/Whh)
__global__ void g1_gemm(const float* __restrict__ rp, const float* __restrict__ h,
                        const float* __restrict__ Wih, const float* __restrict__ Whh,
                        const float* __restrict__ bih, const float* __restrict__ bhh,
                        float* __restrict__ A, float* __restrict__ B) {
    int bI = blockIdx.x;
    int jt = bI % 96, nt = bI / 96;
    int t  = threadIdx.x;
    int tn = t & 15, tj = t >> 4;
    int n  = nt * 16 + tn;
    int j  = jt * 16 + tj;
    __shared__ float act[16][132];   // +4 pad: breaks same-bank row stride
    __shared__ float wt[16][132];
    int lbase = t * 8;
    int lrow  = lbase >> 7, lcol = lbase & 127;
    float accA = 0.f, accB = 0.f;
    for (int c = 0; c < 5; ++c) {
        // stage act chunk
        if (c == 0) {
            int gn = nt * 16 + lrow;
            float4 v0 = {0,0,0,0}, v1 = {0,0,0,0};
            for (int p = 0; p < 8; ++p) {
                const float4* s = (const float4*)(rp + (p * NN + gn) * DD + lcol);
                float4 a = s[0], b = s[1];
                v0.x += a.x; v0.y += a.y; v0.z += a.z; v0.w += a.w;
                v1.x += b.x; v1.y += b.y; v1.z += b.z; v1.w += b.w;
            }
            *(float4*)&act[lrow][lcol]     = v0;
            *(float4*)&act[lrow][lcol + 4] = v1;
            const float4* s = (const float4*)(Wih + (jt * 16 + lrow) * DD + lcol);
            *(float4*)&wt[lrow][lcol]      = s[0];
            *(float4*)&wt[lrow][lcol + 4]  = s[1];
        } else {
            int koff = (c - 1) * 128;
            const float4* s = (const float4*)(h + (nt * 16 + lrow) * HH + koff + lcol);
            *(float4*)&act[lrow][lcol]     = s[0];
            *(float4*)&act[lrow][lcol + 4] = s[1];
            const float4* w = (const float4*)(Whh + (jt * 16 + lrow) * HH + koff + lcol);
            *(float4*)&wt[lrow][lcol]      = w[0];
            *(float4*)&wt[lrow][lcol + 4]  = w[1];
        }
        __syncthreads();
        float acc = 0.f;
        const float* ar = act[tn];
        const float* wr = wt[tj];
        #pragma unroll
        for (int kk = 0; kk < 128; kk += 4) {
            float4 a4 = *(const float4*)(ar + kk);
            float4 w4 = *(const float4*)(wr + kk);
            acc += a4.x * w4.x + a4.y * w4.y + a4.z * w4.z + a4.w * w4.w;
        }
        if (c == 0) accA = acc; else accB += acc;
        __syncthreads();
    }
    A[n * 1536 + j] = accA + bih[j];
    B[n * 1536 + j] = accB + bhh[j];
}

// ---------- g2: gate fusion -> h_o ----------
__global__ void g2_gates(const float* __restrict__ A, const float* __restrict__ B,
                         const float* __restrict__ hprev, float* __restrict__ ho) {
    int id = blockIdx.x * 256 + threadIdx.x;   // NN*HH
    int n = id >> 9, j = id & 511;
    const float* a = A + n * 1536;
    const float* b = B + n * 1536;
    float ir = a[j], iz = a[512 + j], in_ = a[1024 + j];
    float hr = b[j], hz = b[512 + j], hn  = b[1024 + j];
    float rg = 1.f / (1.f + expf(-(ir + hr)));
    float zg = 1.f / (1.f + expf(-(iz + hz)));
    float ng = tanhf(in_ + rg * hn);
    ho[id] = (1.f - zg) * ng + zg * hprev[id];
}

// ---------- g3: e = sigmoid(ho@We^T + be), v = ho@Wv^T + bv ----------
// grid 128 = 16 out-tiles x 8 n-tiles; block 256 = 16out x 16n; K = 4x128
__global__ void g3_ev(const float* __restrict__ ho, const float* __restrict__ We,
                      const float* __restrict__ be, const float* __restrict__ Wv,
                      const float* __restrict__ bv, float* __restrict__ e,
                      float* __restrict__ v) {
    int bI = blockIdx.x;
    int jt = bI % 16, nt = bI / 16;
    int t  = threadIdx.x;
    int tn = t & 15, tj = t >> 4;
    int n  = nt * 16 + tn;
    int j  = jt * 16 + tj;           // 0..255: <128 -> e, else v
    __shared__ float act[16][132];
    __shared__ float wt[16][132];
    int lbase = t * 8;
    int lrow  = lbase >> 7, lcol = lbase & 127;
    int wrow  = jt * 16 + lrow;
    const float* Wsrc = (wrow < 128) ? (We + wrow * HH) : (Wv + (wrow - 128) * HH);
    float acc = 0.f;
    for (int c = 0; c < 4; ++c) {
        int koff = c * 128;
        const float4* s = (const float4*)(ho + (nt * 16 + lrow) * HH + koff + lcol);
        *(float4*)&act[lrow][lcol]     = s[0];
        *(float4*)&act[lrow][lcol + 4] = s[1];
        const float4* w = (const float4*)(Wsrc + koff + lcol);
        *(float4*)&wt[lrow][lcol]      = w[0];
        *(float4*)&wt[lrow][lcol + 4]  = w[1];
        __syncthreads();
        const float* ar = act[tn];
        const float* wr = wt[tj];
        #pragma unroll
        for (int kk = 0; kk < 128; kk += 4) {
            float4 a4 = *(const float4*)(ar + kk);
            float4 w4 = *(const float4*)(wr + kk);
            acc += a4.x * w4.x + a4.y * w4.y + a4.z * w4.z + a4.w * w4.w;
        }
        __syncthreads();
    }
    if (j < 128) e[n * DD + j] = 1.f / (1.f + expf(-(acc + be[j])));
    else         v[n * DD + (j - 128)] = acc + bv[j - 128];
}

__global__ void k6_cnew(const float* __restrict__ c_prev, const float* __restrict__ wc,
                        const float* __restrict__ e, const float* __restrict__ v,
                        float* __restrict__ out) {
    int i  = blockIdx.x * 256 + threadIdx.x;
    int nm = i >> 5;
    int d4 = i & 31;
    int n  = nm >> 11;
    float w = wc[nm];
    float4 c4 = ((const float4*)c_prev)[i];
    float4 e4 = ((const float4*)e)[n * 32 + d4];
    float4 v4 = ((const float4*)v)[n * 32 + d4];
    float4 o;
    o.x = c4.x * (1.f - w * e4.x) + w * v4.x;
    o.y = c4.y * (1.f - w * e4.y) + w * v4.y;
    o.z = c4.z * (1.f - w * e4.z) + w * v4.z;
    o.w = c4.w * (1.f - w * e4.w) + w * v4.w;
    ((float4*)out)[i] = o;
}

extern "C" void kernel_launch(void* const* d_in, const int* in_sizes, int n_in,
                              void* d_out, int out_size, void* d_ws, size_t ws_size,
                              hipStream_t stream) {
    const float* h_o_prev = (const float*)d_in[0];
    const float* c_prev   = (const float*)d_in[1];
    const float* c_xf     = (const float*)d_in[2];
    const float* Wk       = (const float*)d_in[3];
    const float* bk       = (const float*)d_in[4];
    const float* Wb       = (const float*)d_in[5];
    const float* bb       = (const float*)d_in[6];
    const float* We       = (const float*)d_in[7];
    const float* be       = (const float*)d_in[8];
    const float* Wv       = (const float*)d_in[9];
    const float* bv       = (const float*)d_in[10];
    const float* Wih      = (const float*)d_in[11];
    const float* Whh      = (const float*)d_in[12];
    const float* bih      = (const float*)d_in[13];
    const float* bhh      = (const float*)d_in[14];

    float* ws   = (float*)d_ws;
    float* k    = ws;
    float* kn   = ws + 16384;
    float* beta = ws + 16512;
    float* sx   = ws + 16640;
    float* sc   = ws + 278784;
    float* rp   = ws + 540928;
    float* Bg   = ws + 672000;
    float* e    = ws + 868608;
    float* v    = ws + 884992;
    float* Ag   = sx;   // sx dead after k4

    float* ho_out = (float*)d_out;              // [NN*HH]
    float* c_out  = (float*)d_out + NN * HH;    // [NN*MM*DD]

    k1_kbeta<<<NN, 128, 0, stream>>>(h_o_prev, Wk, bk, Wb, bb, k, kn, beta);
    k2_scores<<<NN * MM / 8, 256, 0, stream>>>(c_prev, c_xf, k, kn, beta, sx, sc);
    k3_softmax<<<2 * NN, 256, 0, stream>>>(sx, sc);
    k4_r<<<NN * 8, 256, 0, stream>>>(c_xf, sx, rp);
    g1_gemm<<<768, 256, 0, stream>>>(rp, h_o_prev, Wih, Whh, bih, bhh, Ag, Bg);
    g2_gates<<<NN * HH / 256, 256, 0, stream>>>(Ag, Bg, h_o_prev, ho_out);
    g3_ev<<<128, 256, 0, stream>>>(ho_out, We, be, Wv, bv, e, v);
    k6_cnew<<<NN * MM * DD / 4 / 256, 256, 0, stream>>>(c_prev, sc, e, v, c_out);
}

// Round 3
// 143.668 us; speedup vs baseline: 3.0580x; 1.3572x over previous
//
#include <hip/hip_runtime.h>
#include <math.h>

#define NN 128
#define HH 512
#define MM 2048
#define DD 128
#define EPSF 1e-8f

// ---------------- workspace layout (floats) ----------------
// k    : [NN*DD]          off 0
// kn   : [NN]             off 16384
// beta : [NN]             off 16512
// sc   : [NN*MM]          off 16640   raw c_prev scores (live till k6)
// rp   : [32*NN*DD]       off 278784  xf online-softmax partial accs (dead after kB)
// cmx  : [NN*32]          off 803072  xf chunk max
// clx  : [NN*32]          off 807168  xf chunk expsum
// cmc  : [NN*32]          off 811264  prev chunk max
// clc  : [NN*32]          off 815360  prev chunk expsum
// r    : [NN*DD]          off 819456
// muc  : [NN]             off 835840
// invLc: [NN]             off 835968
// e    : [NN*DD]          off 836096
// v    : [NN*DD]          off 852480  -> end 868864 floats = 3.48 MB
// A (gi gates) aliases rp @278784 (196608), B (gh gates) aliases rp @475392.

__global__ void k1_kbeta(const float* __restrict__ h, const float* __restrict__ Wk,
                         const float* __restrict__ bk, const float* __restrict__ Wb,
                         const float* __restrict__ bb, float* __restrict__ k,
                         float* __restrict__ kn, float* __restrict__ beta) {
    int n = blockIdx.x;
    int t = threadIdx.x;            // 128 threads
    __shared__ float hs[HH];
    __shared__ float red[128];
    for (int i = t; i < HH; i += 128) hs[i] = h[n * HH + i];
    __syncthreads();
    float acc = bk[t];
    const float* wr = Wk + t * HH;
    for (int hh = 0; hh < HH; hh += 4) {
        float4 w4 = *(const float4*)(wr + hh);
        acc += w4.x * hs[hh] + w4.y * hs[hh + 1] + w4.z * hs[hh + 2] + w4.w * hs[hh + 3];
    }
    k[n * DD + t] = acc;
    red[t] = acc * acc;
    __syncthreads();
    for (int s = 64; s > 0; s >>= 1) { if (t < s) red[t] += red[t + s]; __syncthreads(); }
    if (t == 0) kn[n] = fmaxf(sqrtf(red[0]), EPSF);
    __syncthreads();
    float b = 0.f;
    for (int i = t; i < HH; i += 128) b += hs[i] * Wb[i];
    red[t] = b;
    __syncthreads();
    for (int s = 64; s > 0; s >>= 1) { if (t < s) red[t] += red[t + s]; __syncthreads(); }
    if (t == 0) {
        float bp   = red[0] + bb[0];
        float bpos = fmaxf(bp, 0.f);
        float bneg = fminf(bp, 0.f);
        beta[n] = log1pf(expf(bneg)) + bpos + log1pf(expf(-bpos))
                + (1.f - 0.69314718055994530942f);
    }
}

// ---------- kA: scores via per-lane rows; xf branch fuses online-softmax r-partials ----------
// grid 8192 = n(128) x chunk(32) x arr(2); block 256. 64 m-rows per block.
// LDS tile XOR-swizzled in 16B groups: conflict-free row reads AND column reads.
__global__ void kA_scores(const float* __restrict__ c_prev, const float* __restrict__ c_xf,
                          const float* __restrict__ kv, const float* __restrict__ kn,
                          const float* __restrict__ beta,
                          float* __restrict__ sc, float* __restrict__ rp,
                          float* __restrict__ cmx, float* __restrict__ clx,
                          float* __restrict__ cmc, float* __restrict__ clc) {
    int b     = blockIdx.x;
    int arr   = b & 1;              // 0 = c_xf (r path), 1 = c_prev (sc path)
    int chunk = (b >> 1) & 31;
    int n     = b >> 6;
    int t     = threadIdx.x;
    __shared__ float tile[64 * 128];
    __shared__ float kl[128];
    __shared__ float redD[256];
    __shared__ float redN[256];
    __shared__ float ps[64];

    const float*  src  = arr ? c_prev : c_xf;
    const float4* src4 = (const float4*)src + (size_t)(n * MM + chunk * 64) * 32;
    #pragma unroll
    for (int i = 0; i < 8; i++) {
        int fid = t + 256 * i;
        int row = fid >> 5, c4 = fid & 31;
        float4 vld = src4[fid];
        int c4s = c4 ^ (row & 7);
        *(float4*)&tile[row * 128 + c4s * 4] = vld;
    }
    if (t < 128) kl[t] = kv[n * DD + t];
    __syncthreads();
    float sb = beta[n] / kn[n];

    // scores: row = t&63 owns a row, quarter q = t>>6 covers d = q*32..q*32+31
    int row = t & 63, q = t >> 6;
    float dk = 0.f, nn = 0.f;
    #pragma unroll
    for (int j = 0; j < 8; j++) {
        int g  = q * 8 + j;               // 16B group 0..31
        int gs = g ^ (row & 7);
        float4 cv = *(const float4*)&tile[row * 128 + gs * 4];
        float4 kk = *(const float4*)&kl[g * 4];
        dk += cv.x * kk.x + cv.y * kk.y + cv.z * kk.z + cv.w * kk.w;
        nn += cv.x * cv.x + cv.y * cv.y + cv.z * cv.z + cv.w * cv.w;
    }
    redD[t] = dk; redN[t] = nn;
    __syncthreads();
    float s = 0.f;
    if (t < 64) {
        dk = redD[t] + redD[t + 64] + redD[t + 128] + redD[t + 192];
        nn = redN[t] + redN[t + 64] + redN[t + 128] + redN[t + 192];
        s  = dk / fmaxf(sqrtf(nn), EPSF) * sb;
        if (arr) sc[n * MM + chunk * 64 + t] = s;
    }
    __syncthreads();
    // block max over 64 scores
    redD[t] = (t < 64) ? s : -1e30f;
    __syncthreads();
    for (int st = 32; st >= 1; st >>= 1) {
        if (t < st) redD[t] = fmaxf(redD[t], redD[t + st]);
        __syncthreads();
    }
    float mu = redD[0];
    if (t < 64) { float p = expf(s - mu); ps[t] = p; redN[t] = p; }
    __syncthreads();
    for (int st = 32; st >= 1; st >>= 1) {
        if (t < st) redN[t] += redN[t + st];
        __syncthreads();
    }
    float lb = redN[0];

    if (arr) {
        if (t == 0) { cmc[n * 32 + chunk] = mu; clc[n * 32 + chunk] = lb; }
        return;
    }
    // xf: partial weighted accumulate over this chunk's 64 rows
    int d = t & 127, half = t >> 7;
    float acc = 0.f;
    #pragma unroll 8
    for (int m = 0; m < 32; m++) {
        int mm  = half * 32 + m;
        int idx = mm * 128 + (((d >> 2) ^ (mm & 7)) << 2) + (d & 3);
        acc += ps[mm] * tile[idx];
    }
    redD[t] = acc;
    __syncthreads();
    if (t < 128) rp[((size_t)n * 32 + chunk) * 128 + t] = redD[t] + redD[t + 128];
    if (t == 0) { cmx[n * 32 + chunk] = mu; clx[n * 32 + chunk] = lb; }
}

// ---------- kB: merge 32 chunk partials per n -> r[n,:], and prev (mu, 1/L) ----------
__global__ void kB_combine(const float* __restrict__ rp, const float* __restrict__ cmx,
                           const float* __restrict__ clx, const float* __restrict__ cmc,
                           const float* __restrict__ clc, float* __restrict__ r,
                           float* __restrict__ muc, float* __restrict__ invLc) {
    int n = blockIdx.x;
    int t = threadIdx.x;            // 128
    float mu = -1e30f;
    for (int c = 0; c < 32; c++) mu = fmaxf(mu, cmx[n * 32 + c]);
    float L = 0.f, acc = 0.f;
    for (int c = 0; c < 32; c++) {
        float w = expf(cmx[n * 32 + c] - mu);
        L   += w * clx[n * 32 + c];
        acc += w * rp[((size_t)n * 32 + c) * 128 + t];
    }
    r[n * DD + t] = acc / L;
    if (t == 0) {
        float m2 = -1e30f;
        for (int c = 0; c < 32; c++) m2 = fmaxf(m2, cmc[n * 32 + c]);
        float L2 = 0.f;
        for (int c = 0; c < 32; c++) L2 += expf(cmc[n * 32 + c] - m2) * clc[n * 32 + c];
        muc[n] = m2; invLc[n] = 1.f / L2;
    }
}

// ---------- g1: A = r@Wih^T + bih, B = h@Whh^T + bhh  ([NN,1536] each) ----------
__global__ void g1_gemm(const float* __restrict__ rf, const float* __restrict__ h,
                        const float* __restrict__ Wih, const float* __restrict__ Whh,
                        const float* __restrict__ bih, const float* __restrict__ bhh,
                        float* __restrict__ A, float* __restrict__ B) {
    int bI = blockIdx.x;
    int jt = bI % 96, nt = bI / 96;
    int t  = threadIdx.x;
    int tn = t & 15, tj = t >> 4;
    int n  = nt * 16 + tn;
    int j  = jt * 16 + tj;
    __shared__ float act[16][132];
    __shared__ float wt[16][132];
    int lbase = t * 8;
    int lrow  = lbase >> 7, lcol = lbase & 127;
    float accA = 0.f, accB = 0.f;
    for (int c = 0; c < 5; ++c) {
        if (c == 0) {
            int gn = nt * 16 + lrow;
            const float4* s = (const float4*)(rf + gn * DD + lcol);
            *(float4*)&act[lrow][lcol]     = s[0];
            *(float4*)&act[lrow][lcol + 4] = s[1];
            const float4* w = (const float4*)(Wih + (jt * 16 + lrow) * DD + lcol);
            *(float4*)&wt[lrow][lcol]      = w[0];
            *(float4*)&wt[lrow][lcol + 4]  = w[1];
        } else {
            int koff = (c - 1) * 128;
            const float4* s = (const float4*)(h + (nt * 16 + lrow) * HH + koff + lcol);
            *(float4*)&act[lrow][lcol]     = s[0];
            *(float4*)&act[lrow][lcol + 4] = s[1];
            const float4* w = (const float4*)(Whh + (jt * 16 + lrow) * HH + koff + lcol);
            *(float4*)&wt[lrow][lcol]      = w[0];
            *(float4*)&wt[lrow][lcol + 4]  = w[1];
        }
        __syncthreads();
        float acc = 0.f;
        const float* ar = act[tn];
        const float* wr = wt[tj];
        #pragma unroll
        for (int kk = 0; kk < 128; kk += 4) {
            float4 a4 = *(const float4*)(ar + kk);
            float4 w4 = *(const float4*)(wr + kk);
            acc += a4.x * w4.x + a4.y * w4.y + a4.z * w4.z + a4.w * w4.w;
        }
        if (c == 0) accA = acc; else accB += acc;
        __syncthreads();
    }
    A[n * 1536 + j] = accA + bih[j];
    B[n * 1536 + j] = accB + bhh[j];
}

__global__ void g2_gates(const float* __restrict__ A, const float* __restrict__ B,
                         const float* __restrict__ hprev, float* __restrict__ ho) {
    int id = blockIdx.x * 256 + threadIdx.x;   // NN*HH
    int n = id >> 9, j = id & 511;
    const float* a = A + n * 1536;
    const float* b = B + n * 1536;
    float ir = a[j], iz = a[512 + j], in_ = a[1024 + j];
    float hr = b[j], hz = b[512 + j], hn  = b[1024 + j];
    float rg = 1.f / (1.f + expf(-(ir + hr)));
    float zg = 1.f / (1.f + expf(-(iz + hz)));
    float ng = tanhf(in_ + rg * hn);
    ho[id] = (1.f - zg) * ng + zg * hprev[id];
}

__global__ void g3_ev(const float* __restrict__ ho, const float* __restrict__ We,
                      const float* __restrict__ be, const float* __restrict__ Wv,
                      const float* __restrict__ bv, float* __restrict__ e,
                      float* __restrict__ v) {
    int bI = blockIdx.x;
    int jt = bI % 16, nt = bI / 16;
    int t  = threadIdx.x;
    int tn = t & 15, tj = t >> 4;
    int n  = nt * 16 + tn;
    int j  = jt * 16 + tj;
    __shared__ float act[16][132];
    __shared__ float wt[16][132];
    int lbase = t * 8;
    int lrow  = lbase >> 7, lcol = lbase & 127;
    int wrow  = jt * 16 + lrow;
    const float* Wsrc = (wrow < 128) ? (We + wrow * HH) : (Wv + (wrow - 128) * HH);
    float acc = 0.f;
    for (int c = 0; c < 4; ++c) {
        int koff = c * 128;
        const float4* s = (const float4*)(ho + (nt * 16 + lrow) * HH + koff + lcol);
        *(float4*)&act[lrow][lcol]     = s[0];
        *(float4*)&act[lrow][lcol + 4] = s[1];
        const float4* w = (const float4*)(Wsrc + koff + lcol);
        *(float4*)&wt[lrow][lcol]      = w[0];
        *(float4*)&wt[lrow][lcol + 4]  = w[1];
        __syncthreads();
        const float* ar = act[tn];
        const float* wr = wt[tj];
        #pragma unroll
        for (int kk = 0; kk < 128; kk += 4) {
            float4 a4 = *(const float4*)(ar + kk);
            float4 w4 = *(const float4*)(wr + kk);
            acc += a4.x * w4.x + a4.y * w4.y + a4.z * w4.z + a4.w * w4.w;
        }
        __syncthreads();
    }
    if (j < 128) e[n * DD + j] = 1.f / (1.f + expf(-(acc + be[j])));
    else         v[n * DD + (j - 128)] = acc + bv[j - 128];
}

// ---------- k6: c_new = c_prev*(1 - w*e) + w*v, w computed inline from raw scores ----------
__global__ void k6_cnew(const float* __restrict__ c_prev, const float* __restrict__ sc,
                        const float* __restrict__ muc, const float* __restrict__ invLc,
                        const float* __restrict__ e, const float* __restrict__ v,
                        float* __restrict__ out) {
    int i  = blockIdx.x * 256 + threadIdx.x;
    int nm = i >> 5;
    int d4 = i & 31;
    int n  = nm >> 11;
    float w = expf(sc[nm] - muc[n]) * invLc[n];
    float4 c4 = ((const float4*)c_prev)[i];
    float4 e4 = ((const float4*)e)[n * 32 + d4];
    float4 v4 = ((const float4*)v)[n * 32 + d4];
    float4 o;
    o.x = c4.x * (1.f - w * e4.x) + w * v4.x;
    o.y = c4.y * (1.f - w * e4.y) + w * v4.y;
    o.z = c4.z * (1.f - w * e4.z) + w * v4.z;
    o.w = c4.w * (1.f - w * e4.w) + w * v4.w;
    ((float4*)out)[i] = o;
}

extern "C" void kernel_launch(void* const* d_in, const int* in_sizes, int n_in,
                              void* d_out, int out_size, void* d_ws, size_t ws_size,
                              hipStream_t stream) {
    const float* h_o_prev = (const float*)d_in[0];
    const float* c_prev   = (const float*)d_in[1];
    const float* c_xf     = (const float*)d_in[2];
    const float* Wk       = (const float*)d_in[3];
    const float* bk       = (const float*)d_in[4];
    const float* Wb       = (const float*)d_in[5];
    const float* bb       = (const float*)d_in[6];
    const float* We       = (const float*)d_in[7];
    const float* be       = (const float*)d_in[8];
    const float* Wv       = (const float*)d_in[9];
    const float* bv       = (const float*)d_in[10];
    const float* Wih      = (const float*)d_in[11];
    const float* Whh      = (const float*)d_in[12];
    const float* bih      = (const float*)d_in[13];
    const float* bhh      = (const float*)d_in[14];

    float* ws    = (float*)d_ws;
    float* k     = ws;
    float* kn    = ws + 16384;
    float* beta  = ws + 16512;
    float* sc    = ws + 16640;
    float* rp    = ws + 278784;
    float* cmx   = ws + 803072;
    float* clx   = ws + 807168;
    float* cmc   = ws + 811264;
    float* clc   = ws + 815360;
    float* r     = ws + 819456;
    float* muc   = ws + 835840;
    float* invLc = ws + 835968;
    float* e     = ws + 836096;
    float* v     = ws + 852480;
    float* Ag    = ws + 278784;   // aliases rp (dead after kB)
    float* Bg    = ws + 475392;   // aliases rp tail

    float* ho_out = (float*)d_out;              // [NN*HH]
    float* c_out  = (float*)d_out + NN * HH;    // [NN*MM*DD]

    k1_kbeta<<<NN, 128, 0, stream>>>(h_o_prev, Wk, bk, Wb, bb, k, kn, beta);
    kA_scores<<<NN * 32 * 2, 256, 0, stream>>>(c_prev, c_xf, k, kn, beta,
                                               sc, rp, cmx, clx, cmc, clc);
    kB_combine<<<NN, 128, 0, stream>>>(rp, cmx, clx, cmc, clc, r, muc, invLc);
    g1_gemm<<<768, 256, 0, stream>>>(r, h_o_prev, Wih, Whh, bih, bhh, Ag, Bg);
    g2_gates<<<NN * HH / 256, 256, 0, stream>>>(Ag, Bg, h_o_prev, ho_out);
    g3_ev<<<128, 256, 0, stream>>>(ho_out, We, be, Wv, bv, e, v);
    k6_cnew<<<NN * MM * DD / 4 / 256, 256, 0, stream>>>(c_prev, sc, muc, invLc, e, v, c_out);
}